// Round 3
// baseline (861.862 us; speedup 1.0000x reference)
//
#include <hip/hip_runtime.h>
#include <hip/hip_bf16.h>

typedef __bf16 bf16_t;
typedef __bf16 bf16x8 __attribute__((ext_vector_type(8)));
typedef float f32x4 __attribute__((ext_vector_type(4)));

#define DEVINL static __device__ __forceinline__

DEVINL void gload_lds16(const void* g, void* l) {
  __builtin_amdgcn_global_load_lds(
      (__attribute__((address_space(1))) void*)g,
      (__attribute__((address_space(3))) void*)l, 16, 0, 0);
}

// --- merged prep: z<10 = batched transpose ([2048][2048] f32 -> bf16, dst ld)
//     z==10 = x f32 -> bf16 convert + catb bias concat [sd_b0 | rd_b0] ---
struct Prep { const float* s[10]; bf16_t* d[10]; int ld[10];
              const float* x; bf16_t* xb;
              const float* b0a; const float* b0b; float* catb; };
__global__ __launch_bounds__(256) void k_prep(Prep a) {
  if (blockIdx.z == 10) {
    int t = (blockIdx.y * 64 + blockIdx.x) * 256 + threadIdx.x;
    if (t < 4096) a.catb[t] = t < 2048 ? a.b0a[t] : a.b0b[t - 2048];
    const float4* p = (const float4*)a.x + (size_t)t * 2;
    float4 u = p[0], v = p[1];
    bf16x8 o;
    o[0] = (bf16_t)u.x; o[1] = (bf16_t)u.y; o[2] = (bf16_t)u.z; o[3] = (bf16_t)u.w;
    o[4] = (bf16_t)v.x; o[5] = (bf16_t)v.y; o[6] = (bf16_t)v.z; o[7] = (bf16_t)v.w;
    *(bf16x8*)(a.xb + (size_t)t * 8) = o;
    return;
  }
  __shared__ float tile[32][33];
  const int z = blockIdx.z;
  const float* W = a.s[z];
  bf16_t* WT = a.d[z];
  const int dld = a.ld[z];
  int tx = threadIdx.x & 31, ty = threadIdx.x >> 5;
  int n0 = blockIdx.x * 32, k0 = blockIdx.y * 32;
  #pragma unroll
  for (int i = 0; i < 32; i += 8)
    tile[ty + i][tx] = W[(size_t)(k0 + ty + i) * 2048 + n0 + tx];
  __syncthreads();
  #pragma unroll
  for (int i = 0; i < 32; i += 8)
    WT[(size_t)(n0 + ty + i) * dld + k0 + tx] = (bf16_t)tile[tx][ty + i];
}

// ========= BMxBN 8-phase GEMM engine (T1+T2+T3+T4+T5), NW waves (2 x NW/2) =========
// 16x16x32 core (32x32 regressed: bank conflicts — round 2).
// MODE 0: C = act(A @ BT^T); cols < act_ncol get +bias & relu, others raw.
// MODE 2: like MODE 0, but cols in [act_ncol, 2*act_ncol) get +bias[col], NO relu
//         (tuv GEMM: folds rd_b0 into the u-columns; bias = catb [sd_b0|rd_b0]).
// MODE 1 (<256,256,8>): rel path. A is NOT read from memory as-is; instead each
//   A-row p = b*64+i*8+jj (jj==7 pad -> zeros) is generated in-staging as
//   relu(u'[b*8+i] + v[b*8+j]) from A=tuv (u' at col 2048, v at col 4096, ld=lda).
//   Reg-staged (T14 issue-early/write-late); B-side global_load_lds unchanged.
//   Epilogue: fused 8-row-group reduce + xs add.
template <typename TOUT, int BM, int BN, int NW, int MODE>
__global__ __launch_bounds__(NW * 64, 2) void k_gemm(
    const bf16_t* __restrict__ A, const bf16_t* __restrict__ A2, int lda, int ksplit,
    const bf16_t* __restrict__ BT, int ldb,
    const float* __restrict__ bias, int act_ncol,
    TOUT* __restrict__ C, int N, int K,
    const bf16_t* __restrict__ xsp, int drow) {
  constexpr bool FUSE = (MODE == 1);
  constexpr int WN = NW / 2;         // wave grid = 2 (M) x WN (N)
  constexpr int MF = BM / 32;        // A fragments per wave
  constexpr int MH = MF / 2;         // fragments per phase
  constexpr int NF = BN / (16 * WN); // B fragments per wave
  static_assert(NF == 4, "engine assumes 4 B-fragments per wave");
  constexpr int AQ = BM / (16 * NW); // A stage slots per thread per half
  constexpr int BQ = BN / (16 * NW); // B gload_lds per thread per half
  constexpr int AHALF = BM * 64;     // bytes per A k-half
  constexpr int BHALF = BN * 64;     // bytes per B k-half
  constexpr int AREG = 2 * AHALF;
  constexpr int BUFS = AREG + 2 * BHALF;
  constexpr int NWAIT = AQ + 2 * BQ; // (!FUSE) halves of t+2 in flight at tile end

  extern __shared__ char smem[];
  const int t = threadIdx.x;
  const int w = t >> 6, l = t & 63;

  // T1: bijective XCD swizzle (m204)
  const int nwg = gridDim.x * gridDim.y;
  const int bid = blockIdx.y * gridDim.x + blockIdx.x;
  const int q8 = nwg >> 3, r8 = nwg & 7, xcd = bid & 7, sidx = bid >> 3;
  const int wg = (xcd < r8 ? xcd * (q8 + 1) : r8 * (q8 + 1) + (xcd - r8) * q8) + sidx;
  const int NB = gridDim.x;
  // 2x2 supertile mapping (bijective when NB even, M-blocks even, nwg%4==0)
  int mb, nb;
  if (((NB & 1) | (nwg & 3) | ((nwg / NB) & 1)) == 0) {
    int wg2 = wg >> 2, r2 = wg & 3, sc = NB >> 1;
    mb = (wg2 / sc) * 2 + (r2 >> 1);
    nb = (wg2 % sc) * 2 + (r2 & 1);
  } else {
    mb = wg / NB; nb = wg % NB;
  }
  const int m0 = mb * BM, n0 = nb * BN;

  // ---- staging coords: half h: 0=B-k0, 1=A-k0, 2=B-k1, 3=A-k1 ----
  size_t Aoffq[AQ] = {};
  size_t Boffq[BQ];
  if constexpr (!FUSE) {
    #pragma unroll
    for (int q = 0; q < AQ; ++q) {
      int r = w * (BM / NW) + q * 16 + (l >> 2);
      int sq = (((l & 3) ^ ((r >> 1) & 3))) * 8;  // pre-swizzled k-seg (involution)
      Aoffq[q] = (size_t)(m0 + r) * lda + sq;
    }
  }
  #pragma unroll
  for (int q = 0; q < BQ; ++q) {
    int r = w * (BN / NW) + q * 16 + (l >> 2);
    int sq = (((l & 3) ^ ((r >> 1) & 3))) * 8;
    Boffq[q] = (size_t)(n0 + r) * ldb + sq;
  }
  const int nkt = K >> 6;

  // ---- FUSE: per-thread A-generation coords (row p = b*64 + i*8 + jj) ----
  const bf16_t* uB[AQ]; const bf16_t* vB[AQ]; bool vld[AQ]; int wofs[AQ];
  if constexpr (FUSE) {
    #pragma unroll
    for (int q = 0; q < AQ; ++q) {
      int r = w * (BM / NW) + q * 16 + (l >> 2);
      int p = m0 + r;
      int bq = p >> 6, q6 = p & 63, i = q6 >> 3, jj = q6 & 7;
      vld[q] = (jj != 7);
      int j = jj + (jj >= i ? 1 : 0);
      int sq = (((l & 3) ^ ((r >> 1) & 3))) * 8;
      uB[q] = A + (size_t)(bq * 8 + i) * lda + 2048 + sq;
      vB[q] = A + (size_t)(bq * 8 + j) * lda + 4096 + sq;
      wofs[q] = w * (AHALF / NW) + q * 1024 + l * 16;
    }
  }
  struct AR { bf16x8 u[AQ], v[AQ]; };
  auto loadA = [&](int tau, int kh) {
    AR ar;
    #pragma unroll
    for (int q = 0; q < AQ; ++q) {
      if (vld[q]) {
        int c = tau * 64 + kh * 32;
        ar.u[q] = *(const bf16x8*)(uB[q] + c);
        ar.v[q] = *(const bf16x8*)(vB[q] + c);
      } else {
        ar.u[q] = bf16x8{}; ar.v[q] = bf16x8{};
      }
    }
    return ar;
  };
  auto writeA = [&](const AR& ar, int buf, int kh) {
    #pragma unroll
    for (int q = 0; q < AQ; ++q) {
      bf16x8 h;
      #pragma unroll
      for (int e = 0; e < 8; ++e)
        h[e] = (bf16_t)fmaxf((float)ar.u[q][e] + (float)ar.v[q][e], 0.f);
      *(bf16x8*)(smem + buf * BUFS + kh * AHALF + wofs[q]) = h;
    }
  };
  AR pend;  // A-k0 of next tile (written at P1 into that tile's buffer)

  auto stage = [&](int tau, int buf, int h) {
    const int isA = h & 1, kh = h >> 1;
    char* lb = smem + buf * BUFS + (isA ? kh * AHALF : AREG + kh * BHALF) +
               w * (isA ? (AHALF / NW) : (BHALF / NW));
    const int kk = tau * 64 + kh * 32;
    if (isA) {
      const bf16_t* Ab = A;
      int sub = 0;
      if (A2 != nullptr && tau * 64 >= ksplit) { Ab = A2; sub = ksplit; }
      #pragma unroll
      for (int q = 0; q < AQ; ++q)
        gload_lds16(Ab + Aoffq[q] + (kk - sub), lb + q * 1024);
    } else {
      #pragma unroll
      for (int q = 0; q < BQ; ++q)
        gload_lds16(BT + Boffq[q] + kk, lb + q * 1024);
    }
  };

  // ---- compute-side fragment LDS byte offsets (kh0; +AHALF / +BHALF for kh1) ----
  const int wm = w / WN, wn = w % WN;
  const int lr = l & 15, lg = l >> 4;
  int aoff[MF], boff[NF];
  #pragma unroll
  for (int mf = 0; mf < MF; ++mf) {
    int r = wm * (BM / 2) + mf * 16 + lr;
    aoff[mf] = r * 64 + ((lg ^ ((r >> 1) & 3)) << 4);
  }
  #pragma unroll
  for (int nf = 0; nf < NF; ++nf) {
    int r = wn * 64 + nf * 16 + lr;
    boff[nf] = AREG + r * 64 + ((lg ^ ((r >> 1) & 3)) << 4);
  }

  f32x4 acc[MF][NF] = {};

  // ---- prologue: tile0 fully + 3 halves of tile1 ----
  if constexpr (FUSE) {
    stage(0, 0, 0);                 // B0-k0
    AR a00 = loadA(0, 0);
    stage(0, 0, 2);                 // B0-k1
    AR a01 = loadA(0, 1);
    int t1 = nkt > 1 ? 1 : 0;
    stage(t1, 1, 0);                // B1-k0
    pend = loadA(t1, 0);            // A1-k0 (written at tile0 P1)
    stage(t1, 1, 2);                // B1-k1
    writeA(a00, 0, 0);              // compiler inserts precise vmcnt waits
    writeA(a01, 0, 1);
    asm volatile("s_waitcnt lgkmcnt(0)" ::: "memory");
    __builtin_amdgcn_sched_barrier(0);
    __builtin_amdgcn_s_barrier();
  } else {
    #pragma unroll
    for (int h = 0; h < 4; ++h) stage(0, 0, h);
    {
      int t1 = nkt > 1 ? 1 : 0;
      stage(t1, 1, 0); stage(t1, 1, 1); stage(t1, 1, 2);
    }
    if constexpr (NWAIT == 6) asm volatile("s_waitcnt vmcnt(6)");
    else                      asm volatile("s_waitcnt vmcnt(5)");
    __builtin_amdgcn_sched_barrier(0);
    __builtin_amdgcn_s_barrier();
  }

  auto tile_body = [&](int tile, int buf) {
    char* base = smem + buf * BUFS;
    const int tn1 = (tile + 1 < nkt) ? tile + 1 : nkt - 1;
    const int tn2 = (tile + 2 < nkt) ? tile + 2 : nkt - 1;
    bf16x8 af[MH], bfr[NF];
    AR ak1;

    // phase 1: kh0, m-low ; stage/load (t+1, A-k1); write pend A-k0(t+1) -> buf^1
    #pragma unroll
    for (int nf = 0; nf < NF; ++nf) bfr[nf] = *(const bf16x8*)(base + boff[nf]);
    #pragma unroll
    for (int mf = 0; mf < MH; ++mf) af[mf] = *(const bf16x8*)(base + aoff[mf]);
    if constexpr (FUSE) ak1 = loadA(tn1, 1);
    else                stage(tn1, buf ^ 1, 3);
    __builtin_amdgcn_s_setprio(1);
    #pragma unroll
    for (int mf = 0; mf < MH; ++mf)
      #pragma unroll
      for (int nf = 0; nf < NF; ++nf)
        acc[mf][nf] = __builtin_amdgcn_mfma_f32_16x16x32_bf16(af[mf], bfr[nf], acc[mf][nf], 0, 0, 0);
    __builtin_amdgcn_s_setprio(0);
    if constexpr (FUSE) writeA(pend, buf ^ 1, 0);
    __builtin_amdgcn_sched_barrier(0);
    __builtin_amdgcn_s_barrier();

    // phase 2: kh0, m-high ; stage (t+2, B-k0) -> buf
    #pragma unroll
    for (int mf = 0; mf < MH; ++mf) af[mf] = *(const bf16x8*)(base + aoff[MH + mf]);
    stage(tn2, buf, 0);
    __builtin_amdgcn_s_setprio(1);
    #pragma unroll
    for (int mf = 0; mf < MH; ++mf)
      #pragma unroll
      for (int nf = 0; nf < NF; ++nf)
        acc[MH + mf][nf] = __builtin_amdgcn_mfma_f32_16x16x32_bf16(af[mf], bfr[nf], acc[MH + mf][nf], 0, 0, 0);
    __builtin_amdgcn_s_setprio(0);
    __builtin_amdgcn_sched_barrier(0);
    __builtin_amdgcn_s_barrier();

    // phase 3: kh1, m-low ; load (t+2, A-k0) -> pend ; write A-k1(t+1) -> buf^1
    #pragma unroll
    for (int nf = 0; nf < NF; ++nf) bfr[nf] = *(const bf16x8*)(base + BHALF + boff[nf]);
    #pragma unroll
    for (int mf = 0; mf < MH; ++mf) af[mf] = *(const bf16x8*)(base + AHALF + aoff[mf]);
    if constexpr (FUSE) pend = loadA(tn2, 0);
    else                stage(tn2, buf, 1);
    __builtin_amdgcn_s_setprio(1);
    #pragma unroll
    for (int mf = 0; mf < MH; ++mf)
      #pragma unroll
      for (int nf = 0; nf < NF; ++nf)
        acc[mf][nf] = __builtin_amdgcn_mfma_f32_16x16x32_bf16(af[mf], bfr[nf], acc[mf][nf], 0, 0, 0);
    __builtin_amdgcn_s_setprio(0);
    if constexpr (FUSE) writeA(ak1, buf ^ 1, 1);
    __builtin_amdgcn_sched_barrier(0);
    __builtin_amdgcn_s_barrier();

    // phase 4: kh1, m-high ; stage (t+2, B-k1) -> buf
    #pragma unroll
    for (int mf = 0; mf < MH; ++mf) af[mf] = *(const bf16x8*)(base + AHALF + aoff[MH + mf]);
    stage(tn2, buf, 2);
    __builtin_amdgcn_s_setprio(1);
    #pragma unroll
    for (int mf = 0; mf < MH; ++mf)
      #pragma unroll
      for (int nf = 0; nf < NF; ++nf)
        acc[MH + mf][nf] = __builtin_amdgcn_mfma_f32_16x16x32_bf16(af[mf], bfr[nf], acc[MH + mf][nf], 0, 0, 0);
    __builtin_amdgcn_s_setprio(0);
    if constexpr (FUSE) {
      asm volatile("s_waitcnt lgkmcnt(0)" ::: "memory");  // drain P1/P3 ds_writes
    } else {
      if constexpr (NWAIT == 6) asm volatile("s_waitcnt vmcnt(6)");
      else                      asm volatile("s_waitcnt vmcnt(5)");
    }
    __builtin_amdgcn_sched_barrier(0);
    __builtin_amdgcn_s_barrier();
  };

  for (int tt = 0; tt < nkt; tt += 2) {
    tile_body(tt, 0);
    tile_body(tt + 1, 1);
  }
  asm volatile("s_waitcnt vmcnt(0)");

  // ---- epilogue ----
  if constexpr (MODE == 1) {
    // fused 8-row-group reduce: rows jj=0..6 summed (jj==7 = pad), + xs -> pred.
    const int g = lg >> 1;
    const bool hi = (lg & 1) != 0;
    #pragma unroll
    for (int mf = 0; mf < MF; ++mf) {
      #pragma unroll
      for (int nf = 0; nf < NF; ++nf) {
        int col = n0 + wn * 64 + nf * 16 + lr;
        float bv = bias[col];
        float s = fmaxf(acc[mf][nf][0] + bv, 0.f) +
                  fmaxf(acc[mf][nf][1] + bv, 0.f) +
                  fmaxf(acc[mf][nf][2] + bv, 0.f);
        if (!hi) s += fmaxf(acc[mf][nf][3] + bv, 0.f);  // jj==7 pad excluded
        s += __shfl_xor(s, 16, 64);
        if (!hi) {
          int d = drow + (m0 >> 3) + wm * (BM >> 4) + mf * 2 + g;
          float xv = (float)xsp[(size_t)d * N + col];
          C[(size_t)d * N + col] = (TOUT)(xv + s);
        }
      }
    }
  } else {
    #pragma unroll
    for (int mf = 0; mf < MF; ++mf) {
      #pragma unroll
      for (int nf = 0; nf < NF; ++nf) {
        int col = n0 + wn * 64 + nf * 16 + lr;
        bool act = col < act_ncol;
        float bv;
        if constexpr (MODE == 2) bv = (col < 2 * act_ncol) ? bias[col] : 0.f;
        else                     bv = act ? bias[col] : 0.f;
        #pragma unroll
        for (int ri = 0; ri < 4; ++ri) {
          int row = m0 + wm * (BM / 2) + mf * 16 + lg * 4 + ri;
          float v = acc[mf][nf][ri] + bv;
          if (act) v = fmaxf(v, 0.f);
          C[(size_t)row * N + col] = (TOUT)v;
        }
      }
    }
  }
}

extern "C" void kernel_launch(void* const* d_in, const int* in_sizes, int n_in,
                              void* d_out, int out_size, void* d_ws, size_t ws_size,
                              hipStream_t stream) {
  const float* x     = (const float*)d_in[0];
  const float* sd_w0 = (const float*)d_in[2];
  const float* sd_b0 = (const float*)d_in[3];
  const float* sd_w1 = (const float*)d_in[4];
  const float* sd_b1 = (const float*)d_in[5];
  const float* rd_w0 = (const float*)d_in[6];
  const float* rd_b0 = (const float*)d_in[7];
  const float* rd_w1 = (const float*)d_in[8];
  const float* rd_b1 = (const float*)d_in[9];
  const float* af_w0 = (const float*)d_in[10];
  const float* af_b0 = (const float*)d_in[11];
  const float* af_w1 = (const float*)d_in[12];
  const float* af_b1 = (const float*)d_in[13];
  const float* ag_w0 = (const float*)d_in[14];
  const float* ag_b0 = (const float*)d_in[15];
  const float* ag_w1 = (const float*)d_in[16];
  const float* ag_b1 = (const float*)d_in[17];
  float* out = (float*)d_out;

  const int D = 2048, M = 4096;
  const size_t DD = (size_t)D * D;
  const size_t MN = (size_t)M * D;
  const int MP = 32768;              // padded pair-rows total (512 batches x 64)
  const size_t LDS256 = 131072, LDS128 = 98304;

  hipFuncSetAttribute((const void*)k_gemm<bf16_t, 256, 256, 8, 1>,
                      hipFuncAttributeMaxDynamicSharedMemorySize, (int)LDS256);
  hipFuncSetAttribute((const void*)k_gemm<bf16_t, 128, 256, 8, 0>,
                      hipFuncAttributeMaxDynamicSharedMemorySize, (int)LDS256);
  hipFuncSetAttribute((const void*)k_gemm<bf16_t, 128, 256, 8, 2>,
                      hipFuncAttributeMaxDynamicSharedMemorySize, (int)LDS256);
  hipFuncSetAttribute((const void*)k_gemm<float, 128, 256, 8, 0>,
                      hipFuncAttributeMaxDynamicSharedMemorySize, (int)LDS256);

  char* wp = (char*)d_ws;
  auto alloc = [&](size_t bytes) -> void* {
    void* p = (void*)wp;
    wp += (bytes + 255) & ~(size_t)255;
    return p;
  };
  bf16_t* xb    = (bf16_t*)alloc(MN * 2);                 // 16 MB
  bf16_t* wcat  = (bf16_t*)alloc((size_t)3 * DD * 2);     // 24 MB
  bf16_t* sdw1T = (bf16_t*)alloc(DD * 2);
  bf16_t* rdw1T = (bf16_t*)alloc(DD * 2);
  bf16_t* afw0T = (bf16_t*)alloc(DD * 2);
  bf16_t* afw1T = (bf16_t*)alloc(DD * 2);
  bf16_t* agw0T = (bf16_t*)alloc(DD * 4);                 // [2048][4096]
  bf16_t* agw1T = (bf16_t*)alloc(DD * 2);
  float*  catb  = (float*)alloc((size_t)2 * D * 4);       // [sd_b0 | rd_b0]
  bf16_t* tuv   = (bf16_t*)alloc(MN * 3 * 2);             // 48 MB: [t0|u'|v], ld 6144
  bf16_t* xs    = (bf16_t*)alloc(MN * 2);                 // 16 MB
  bf16_t* S1    = (bf16_t*)alloc(MN * 2);                 // late-stage scratch
  bf16_t* S2    = (bf16_t*)alloc(MN * 2);
  bf16_t* predb = (bf16_t*)alloc(MN * 2);                 // 16 MB
  (void)ws_size; (void)in_sizes; (void)n_in; (void)out_size;

  // 1+2. merged prep: x->bf16 + catb (z=10) + all weight transposes (z<10)
  Prep tp;
  tp.s[0] = sd_w0;           tp.d[0] = wcat;            tp.ld[0] = D;
  tp.s[1] = rd_w0;           tp.d[1] = wcat + DD;       tp.ld[1] = D;
  tp.s[2] = rd_w0 + DD;      tp.d[2] = wcat + 2 * DD;   tp.ld[2] = D;
  tp.s[3] = sd_w1;           tp.d[3] = sdw1T;           tp.ld[3] = D;
  tp.s[4] = rd_w1;           tp.d[4] = rdw1T;           tp.ld[4] = D;
  tp.s[5] = af_w0;           tp.d[5] = afw0T;           tp.ld[5] = D;
  tp.s[6] = af_w1;           tp.d[6] = afw1T;           tp.ld[6] = D;
  tp.s[7] = ag_w1;           tp.d[7] = agw1T;           tp.ld[7] = D;
  tp.s[8] = ag_w0;           tp.d[8] = agw0T;           tp.ld[8] = 2 * D;
  tp.s[9] = ag_w0 + DD;      tp.d[9] = agw0T + D;       tp.ld[9] = 2 * D;
  tp.x = x; tp.xb = xb;
  tp.b0a = sd_b0; tp.b0b = rd_b0; tp.catb = catb;
  k_prep<<<dim3(64, 64, 11), 256, 0, stream>>>(tp);

  dim3 g128(D / 256, M / 128);   // (8, 32) = 256 blocks, 100% fill, 1 round

  // 3+5 merged (MODE 2): tuv = [relu(xb@sd_w0+sd_b0) | xb@Wtop + rd_b0 | xb@Wbot]
  k_gemm<bf16_t, 128, 256, 8, 2><<<dim3(24, 32), 512, LDS128, stream>>>(
      xb, nullptr, D, 0, wcat, D, catb, D, tuv, 3 * D, D, nullptr, 0);
  // 4. xs = relu(t0 @ sd_w1 + sd_b1)   (A = tuv t0-part, lda 6144)
  k_gemm<bf16_t, 128, 256, 8, 0><<<g128, 512, LDS128, stream>>>(
      tuv, nullptr, 3 * D, 0, sdw1T, D, sd_b1, D, xs, D, D, nullptr, 0);

  // 6-8. relational path, single fused launch: A generated in-staging from tuv
  // (h1 never materialized). grid (8,128) = 1024 blocks = 4 exact rounds.
  k_gemm<bf16_t, 256, 256, 8, 1><<<dim3(D / 256, MP / 256), 512, LDS256, stream>>>(
      tuv, nullptr, 3 * D, 0, rdw1T, D, rd_b1, D, predb, D, D, xs, 0);

  // 9. S1 = relu(pred @ af_w0 + af_b0)
  k_gemm<bf16_t, 128, 256, 8, 0><<<g128, 512, LDS128, stream>>>(
      predb, nullptr, D, 0, afw0T, D, af_b0, D, S1, D, D, nullptr, 0);
  // 10. S2 = relu(S1 @ af_w1 + af_b1)
  k_gemm<bf16_t, 128, 256, 8, 0><<<g128, 512, LDS128, stream>>>(
      S1, nullptr, D, 0, afw1T, D, af_b1, D, S2, D, D, nullptr, 0);
  // 11. S1 = relu([S2 ; xb] @ ag_w0 + ag_b0)  (virtual concat at k=D, K=4096)
  k_gemm<bf16_t, 128, 256, 8, 0><<<g128, 512, LDS128, stream>>>(
      S2, xb, D, D, agw0T, 2 * D, ag_b0, D, S1, D, 2 * D, nullptr, 0);
  // 12. out = relu(S1 @ ag_w1 + ag_b1) -> f32
  k_gemm<float, 128, 256, 8, 0><<<g128, 512, LDS128, stream>>>(
      S1, nullptr, D, 0, agw1T, D, ag_b1, D, out, D, D, nullptr, 0);
}

// Round 4
// 697.691 us; speedup vs baseline: 1.2353x; 1.2353x over previous
//
#include <hip/hip_runtime.h>
#include <hip/hip_bf16.h>

typedef __bf16 bf16_t;
typedef __bf16 bf16x8 __attribute__((ext_vector_type(8)));
typedef float f32x4 __attribute__((ext_vector_type(4)));

#define DEVINL static __device__ __forceinline__

DEVINL void gload_lds16(const void* g, void* l) {
  __builtin_amdgcn_global_load_lds(
      (__attribute__((address_space(1))) void*)g,
      (__attribute__((address_space(3))) void*)l, 16, 0, 0);
}

// --- merged prep: z<10 = batched transpose ([2048][2048] f32 -> bf16, dst ld)
//     z==10 = x f32 -> bf16 convert (64x64 blocks * 256 thr * 8 = 4096*2048) ---
struct Prep { const float* s[10]; bf16_t* d[10]; int ld[10]; const float* x; bf16_t* xb; };
__global__ __launch_bounds__(256) void k_prep(Prep a) {
  if (blockIdx.z == 10) {
    int t = (blockIdx.y * 64 + blockIdx.x) * 256 + threadIdx.x;
    const float4* p = (const float4*)a.x + (size_t)t * 2;
    float4 u = p[0], v = p[1];
    bf16x8 o;
    o[0] = (bf16_t)u.x; o[1] = (bf16_t)u.y; o[2] = (bf16_t)u.z; o[3] = (bf16_t)u.w;
    o[4] = (bf16_t)v.x; o[5] = (bf16_t)v.y; o[6] = (bf16_t)v.z; o[7] = (bf16_t)v.w;
    *(bf16x8*)(a.xb + (size_t)t * 8) = o;
    return;
  }
  __shared__ float tile[32][33];
  const int z = blockIdx.z;
  const float* W = a.s[z];
  bf16_t* WT = a.d[z];
  const int dld = a.ld[z];
  int tx = threadIdx.x & 31, ty = threadIdx.x >> 5;
  int n0 = blockIdx.x * 32, k0 = blockIdx.y * 32;
  #pragma unroll
  for (int i = 0; i < 32; i += 8)
    tile[ty + i][tx] = W[(size_t)(k0 + ty + i) * 2048 + n0 + tx];
  __syncthreads();
  #pragma unroll
  for (int i = 0; i < 32; i += 8)
    WT[(size_t)(n0 + ty + i) * dld + k0 + tx] = (bf16_t)tile[tx][ty + i];
}

// ------- h1 padded to 8 rows/group: row p = b*64 + i*8 + jj (jj==7 -> zeros) -------
__global__ __launch_bounds__(256) void k_h1(const bf16_t* __restrict__ uv, int ldu,
                                            int uo, int vo,
                                            const float* __restrict__ b0,
                                            bf16_t* __restrict__ h1, int pbase) {
  int pl = blockIdx.x;
  int c0 = threadIdx.x * 8;
  int p = pbase + pl;
  int b = p >> 6, q = p & 63;
  int i = q >> 3, jj = q & 7;
  if (jj == 7) {
    bf16x8 z = {};
    *(bf16x8*)(h1 + (size_t)pl * 2048 + c0) = z;
    return;
  }
  int j = jj + (jj >= i ? 1 : 0);
  bf16x8 u = *(const bf16x8*)(uv + (size_t)(b * 8 + i) * ldu + uo + c0);
  bf16x8 v = *(const bf16x8*)(uv + (size_t)(b * 8 + j) * ldu + vo + c0);
  const float4* bp = (const float4*)(b0 + c0);
  float4 ba = bp[0], bb4 = bp[1];
  float bb[8] = {ba.x, ba.y, ba.z, ba.w, bb4.x, bb4.y, bb4.z, bb4.w};
  bf16x8 h;
  #pragma unroll
  for (int e = 0; e < 8; ++e)
    h[e] = (bf16_t)fmaxf((float)u[e] + (float)v[e] + bb[e], 0.f);
  *(bf16x8*)(h1 + (size_t)pl * 2048 + c0) = h;
}

// ========= BMxBN 8-phase GEMM engine (T1+T2+T3+T4+T5), NW waves (2 x NW/2) =========
// 16x16x32 core. (32x32 regressed: bank conflicts — round 2; in-staging A-gen
// regressed: vmcnt FIFO drain killed the prefetch pipeline — round 3.)
// This round: frag-read software pipelining — phase p issues phase p+1's
// ds_reads before its own MFMA cluster (region-audited safe: no within-tile
// stage targets the next phase's frag region; all 4 halves of the current
// tile are complete before the tile starts, guaranteed by the prior tile's
// vmcnt(6)+barrier). Phase 1 keeps its own reads (cross-tile would race).
// MODE 0: C = act(A @ BT^T); cols < act_ncol get +bias & relu, others raw.
// MODE 1 (<256,256,8> only): fused 8-row-group reduce epilogue (rel path).
template <typename TOUT, int BM, int BN, int NW, int MODE>
__global__ __launch_bounds__(NW * 64, 2) void k_gemm(
    const bf16_t* __restrict__ A, const bf16_t* __restrict__ A2, int lda, int ksplit,
    const bf16_t* __restrict__ BT, int ldb,
    const float* __restrict__ bias, int act_ncol,
    TOUT* __restrict__ C, int N, int K,
    const bf16_t* __restrict__ xsp, int drow) {
  constexpr int WN = NW / 2;         // wave grid = 2 (M) x WN (N)
  constexpr int MF = BM / 32;        // A fragments per wave
  constexpr int MH = MF / 2;         // fragments per phase
  constexpr int NF = BN / (16 * WN); // B fragments per wave
  static_assert(NF == 4, "engine assumes 4 B-fragments per wave");
  constexpr int AQ = BM / (16 * NW); // A gload_lds per thread per half
  constexpr int BQ = BN / (16 * NW); // B gload_lds per thread per half
  constexpr int AHALF = BM * 64;     // bytes per A k-half
  constexpr int BHALF = BN * 64;     // bytes per B k-half
  constexpr int AREG = 2 * AHALF;
  constexpr int BUFS = AREG + 2 * BHALF;
  constexpr int NWAIT = AQ + 2 * BQ; // halves of t+2 in flight at tile end

  extern __shared__ char smem[];
  const int t = threadIdx.x;
  const int w = t >> 6, l = t & 63;

  // T1: bijective XCD swizzle (m204)
  const int nwg = gridDim.x * gridDim.y;
  const int bid = blockIdx.y * gridDim.x + blockIdx.x;
  const int q8 = nwg >> 3, r8 = nwg & 7, xcd = bid & 7, sidx = bid >> 3;
  const int wg = (xcd < r8 ? xcd * (q8 + 1) : r8 * (q8 + 1) + (xcd - r8) * q8) + sidx;
  const int NB = gridDim.x;
  // 2x2 supertile mapping (bijective when NB even, M-blocks even, nwg%4==0)
  int mb, nb;
  if (((NB & 1) | (nwg & 3) | ((nwg / NB) & 1)) == 0) {
    int wg2 = wg >> 2, r2 = wg & 3, sc = NB >> 1;
    mb = (wg2 / sc) * 2 + (r2 >> 1);
    nb = (wg2 % sc) * 2 + (r2 & 1);
  } else {
    mb = wg / NB; nb = wg % NB;
  }
  const int m0 = mb * BM, n0 = nb * BN;

  // ---- staging coords: half h: 0=B-k0, 1=A-k0, 2=B-k1, 3=A-k1 ----
  size_t Aoffq[AQ], Boffq[BQ];
  #pragma unroll
  for (int q = 0; q < AQ; ++q) {
    int r = w * (BM / NW) + q * 16 + (l >> 2);
    int sq = (((l & 3) ^ ((r >> 1) & 3))) * 8;  // pre-swizzled k-seg (involution)
    Aoffq[q] = (size_t)(m0 + r) * lda + sq;
  }
  #pragma unroll
  for (int q = 0; q < BQ; ++q) {
    int r = w * (BN / NW) + q * 16 + (l >> 2);
    int sq = (((l & 3) ^ ((r >> 1) & 3))) * 8;
    Boffq[q] = (size_t)(n0 + r) * ldb + sq;
  }
  const int nkt = K >> 6;

  auto stage = [&](int tau, int buf, int h) {
    const int isA = h & 1, kh = h >> 1;
    char* lb = smem + buf * BUFS + (isA ? kh * AHALF : AREG + kh * BHALF) +
               w * (isA ? (AHALF / NW) : (BHALF / NW));
    const int kk = tau * 64 + kh * 32;
    if (isA) {
      const bf16_t* Ab = A;
      int sub = 0;
      if (A2 != nullptr && tau * 64 >= ksplit) { Ab = A2; sub = ksplit; }
      #pragma unroll
      for (int q = 0; q < AQ; ++q)
        gload_lds16(Ab + Aoffq[q] + (kk - sub), lb + q * 1024);
    } else {
      #pragma unroll
      for (int q = 0; q < BQ; ++q)
        gload_lds16(BT + Boffq[q] + kk, lb + q * 1024);
    }
  };

  // ---- compute-side fragment LDS byte offsets (kh0; +AHALF / +BHALF for kh1) ----
  const int wm = w / WN, wn = w % WN;
  const int lr = l & 15, lg = l >> 4;
  int aoff[MF], boff[NF];
  #pragma unroll
  for (int mf = 0; mf < MF; ++mf) {
    int r = wm * (BM / 2) + mf * 16 + lr;
    aoff[mf] = r * 64 + ((lg ^ ((r >> 1) & 3)) << 4);
  }
  #pragma unroll
  for (int nf = 0; nf < NF; ++nf) {
    int r = wn * 64 + nf * 16 + lr;
    boff[nf] = AREG + r * 64 + ((lg ^ ((r >> 1) & 3)) << 4);
  }

  f32x4 acc[MF][NF] = {};

  // ---- prologue: tile0 fully + 3 halves of tile1 ----
  #pragma unroll
  for (int h = 0; h < 4; ++h) stage(0, 0, h);
  {
    int t1 = nkt > 1 ? 1 : 0;
    stage(t1, 1, 0); stage(t1, 1, 1); stage(t1, 1, 2);
  }
  if constexpr (NWAIT == 6) asm volatile("s_waitcnt vmcnt(6)");
  else                      asm volatile("s_waitcnt vmcnt(5)");
  __builtin_amdgcn_sched_barrier(0);
  __builtin_amdgcn_s_barrier();

  auto tile_body = [&](int tile, int buf) {
    char* base = smem + buf * BUFS;
    const int tn1 = (tile + 1 < nkt) ? tile + 1 : nkt - 1;
    const int tn2 = (tile + 2 < nkt) ? tile + 2 : nkt - 1;
    bf16x8 bfr0[NF], bfr1[NF], af1[MH], af2[MH], af3[MH], af4[MH];

    // phase 1: read own frags (B-kh0 + A-kh0 m-low); stage (t+1, A-k1) -> buf^1;
    //          prefetch P2 frags (A-kh0 m-high); MFMA m-low/kh0.
    #pragma unroll
    for (int nf = 0; nf < NF; ++nf) bfr0[nf] = *(const bf16x8*)(base + boff[nf]);
    #pragma unroll
    for (int mf = 0; mf < MH; ++mf) af1[mf] = *(const bf16x8*)(base + aoff[mf]);
    stage(tn1, buf ^ 1, 3);
    #pragma unroll
    for (int mf = 0; mf < MH; ++mf) af2[mf] = *(const bf16x8*)(base + aoff[MH + mf]);
    __builtin_amdgcn_sched_barrier(0);   // pin prefetch before MFMA cluster
    __builtin_amdgcn_s_setprio(1);
    #pragma unroll
    for (int mf = 0; mf < MH; ++mf)
      #pragma unroll
      for (int nf = 0; nf < NF; ++nf)
        acc[mf][nf] = __builtin_amdgcn_mfma_f32_16x16x32_bf16(af1[mf], bfr0[nf], acc[mf][nf], 0, 0, 0);
    __builtin_amdgcn_s_setprio(0);
    __builtin_amdgcn_sched_barrier(0);
    __builtin_amdgcn_s_barrier();

    // phase 2: stage (t+2, B-k0) -> buf; prefetch P3 frags (B-kh1 + A-kh1 m-low);
    //          MFMA m-high/kh0 (af2 read last phase — latency hidden).
    stage(tn2, buf, 0);
    #pragma unroll
    for (int nf = 0; nf < NF; ++nf) bfr1[nf] = *(const bf16x8*)(base + BHALF + boff[nf]);
    #pragma unroll
    for (int mf = 0; mf < MH; ++mf) af3[mf] = *(const bf16x8*)(base + AHALF + aoff[mf]);
    __builtin_amdgcn_sched_barrier(0);
    __builtin_amdgcn_s_setprio(1);
    #pragma unroll
    for (int mf = 0; mf < MH; ++mf)
      #pragma unroll
      for (int nf = 0; nf < NF; ++nf)
        acc[MH + mf][nf] = __builtin_amdgcn_mfma_f32_16x16x32_bf16(af2[mf], bfr0[nf], acc[MH + mf][nf], 0, 0, 0);
    __builtin_amdgcn_s_setprio(0);
    __builtin_amdgcn_sched_barrier(0);
    __builtin_amdgcn_s_barrier();

    // phase 3: stage (t+2, A-k0) -> buf; prefetch P4 frags (A-kh1 m-high);
    //          MFMA m-low/kh1.
    stage(tn2, buf, 1);
    #pragma unroll
    for (int mf = 0; mf < MH; ++mf) af4[mf] = *(const bf16x8*)(base + AHALF + aoff[MH + mf]);
    __builtin_amdgcn_sched_barrier(0);
    __builtin_amdgcn_s_setprio(1);
    #pragma unroll
    for (int mf = 0; mf < MH; ++mf)
      #pragma unroll
      for (int nf = 0; nf < NF; ++nf)
        acc[mf][nf] = __builtin_amdgcn_mfma_f32_16x16x32_bf16(af3[mf], bfr1[nf], acc[mf][nf], 0, 0, 0);
    __builtin_amdgcn_s_setprio(0);
    __builtin_amdgcn_sched_barrier(0);
    __builtin_amdgcn_s_barrier();

    // phase 4: stage (t+2, B-k1) -> buf; MFMA m-high/kh1; counted vmcnt.
    stage(tn2, buf, 2);
    __builtin_amdgcn_sched_barrier(0);
    __builtin_amdgcn_s_setprio(1);
    #pragma unroll
    for (int mf = 0; mf < MH; ++mf)
      #pragma unroll
      for (int nf = 0; nf < NF; ++nf)
        acc[MH + mf][nf] = __builtin_amdgcn_mfma_f32_16x16x32_bf16(af4[mf], bfr1[nf], acc[MH + mf][nf], 0, 0, 0);
    __builtin_amdgcn_s_setprio(0);
    __builtin_amdgcn_sched_barrier(0);
    if constexpr (NWAIT == 6) asm volatile("s_waitcnt vmcnt(6)");
    else                      asm volatile("s_waitcnt vmcnt(5)");
    __builtin_amdgcn_s_barrier();
  };

  for (int tt = 0; tt < nkt; tt += 2) {
    tile_body(tt, 0);
    tile_body(tt + 1, 1);
  }
  asm volatile("s_waitcnt vmcnt(0)");

  // ---- epilogue ----
  if constexpr (MODE == 1) {
    // fused 8-row-group reduce: rows jj=0..6 summed (jj==7 = pad), + xs -> pred.
    const int g = lg >> 1;
    const bool hi = (lg & 1) != 0;
    #pragma unroll
    for (int mf = 0; mf < MF; ++mf) {
      #pragma unroll
      for (int nf = 0; nf < NF; ++nf) {
        int col = n0 + wn * 64 + nf * 16 + lr;
        float bv = bias[col];
        float s = fmaxf(acc[mf][nf][0] + bv, 0.f) +
                  fmaxf(acc[mf][nf][1] + bv, 0.f) +
                  fmaxf(acc[mf][nf][2] + bv, 0.f);
        if (!hi) s += fmaxf(acc[mf][nf][3] + bv, 0.f);  // jj==7 pad excluded
        s += __shfl_xor(s, 16, 64);
        if (!hi) {
          int d = drow + (m0 >> 3) + wm * (BM >> 4) + mf * 2 + g;
          float xv = (float)xsp[(size_t)d * N + col];
          C[(size_t)d * N + col] = (TOUT)(xv + s);
        }
      }
    }
  } else {
    #pragma unroll
    for (int mf = 0; mf < MF; ++mf) {
      #pragma unroll
      for (int nf = 0; nf < NF; ++nf) {
        int col = n0 + wn * 64 + nf * 16 + lr;
        bool act = col < act_ncol;
        float bv = act ? bias[col] : 0.f;
        #pragma unroll
        for (int ri = 0; ri < 4; ++ri) {
          int row = m0 + wm * (BM / 2) + mf * 16 + lg * 4 + ri;
          float v = acc[mf][nf][ri] + bv;
          if (act) v = fmaxf(v, 0.f);
          C[(size_t)row * N + col] = (TOUT)v;
        }
      }
    }
  }
}

extern "C" void kernel_launch(void* const* d_in, const int* in_sizes, int n_in,
                              void* d_out, int out_size, void* d_ws, size_t ws_size,
                              hipStream_t stream) {
  const float* x     = (const float*)d_in[0];
  const float* sd_w0 = (const float*)d_in[2];
  const float* sd_b0 = (const float*)d_in[3];
  const float* sd_w1 = (const float*)d_in[4];
  const float* sd_b1 = (const float*)d_in[5];
  const float* rd_w0 = (const float*)d_in[6];
  const float* rd_b0 = (const float*)d_in[7];
  const float* rd_w1 = (const float*)d_in[8];
  const float* rd_b1 = (const float*)d_in[9];
  const float* af_w0 = (const float*)d_in[10];
  const float* af_b0 = (const float*)d_in[11];
  const float* af_w1 = (const float*)d_in[12];
  const float* af_b1 = (const float*)d_in[13];
  const float* ag_w0 = (const float*)d_in[14];
  const float* ag_b0 = (const float*)d_in[15];
  const float* ag_w1 = (const float*)d_in[16];
  const float* ag_b1 = (const float*)d_in[17];
  float* out = (float*)d_out;

  const int D = 2048, M = 4096;
  const size_t DD = (size_t)D * D;
  const size_t MN = (size_t)M * D;
  const int MCP = 16384;             // padded pair-rows per chunk (256 batches)
  const size_t LDS256 = 131072, LDS128 = 98304;

  hipFuncSetAttribute((const void*)k_gemm<bf16_t, 256, 256, 8, 1>,
                      hipFuncAttributeMaxDynamicSharedMemorySize, (int)LDS256);
  hipFuncSetAttribute((const void*)k_gemm<bf16_t, 128, 256, 8, 0>,
                      hipFuncAttributeMaxDynamicSharedMemorySize, (int)LDS256);
  hipFuncSetAttribute((const void*)k_gemm<float, 128, 256, 8, 0>,
                      hipFuncAttributeMaxDynamicSharedMemorySize, (int)LDS256);

  char* wp = (char*)d_ws;
  auto alloc = [&](size_t bytes) -> void* {
    void* p = (void*)wp;
    wp += (bytes + 255) & ~(size_t)255;
    return p;
  };
  bf16_t* xb    = (bf16_t*)alloc(MN * 2);                 // 16 MB
  bf16_t* wcat  = (bf16_t*)alloc((size_t)3 * DD * 2);     // 24 MB
  bf16_t* sdw1T = (bf16_t*)alloc(DD * 2);
  bf16_t* rdw1T = (bf16_t*)alloc(DD * 2);
  bf16_t* afw0T = (bf16_t*)alloc(DD * 2);
  bf16_t* afw1T = (bf16_t*)alloc(DD * 2);
  bf16_t* agw0T = (bf16_t*)alloc(DD * 4);                 // [2048][4096]
  bf16_t* agw1T = (bf16_t*)alloc(DD * 2);
  bf16_t* tuv   = (bf16_t*)alloc(MN * 3 * 2);             // 48 MB: [t0|u|v], ld 6144
  bf16_t* xs    = (bf16_t*)alloc(MN * 2);                 // 16 MB
  bf16_t* h1c   = (bf16_t*)alloc((size_t)MCP * D * 2);    // 64 MB (also late scratch)
  bf16_t* predb = (bf16_t*)alloc(MN * 2);                 // 16 MB
  (void)ws_size; (void)in_sizes; (void)n_in; (void)out_size;

  bf16_t* S1 = h1c;            // late-stage scratch aliased into h1c
  bf16_t* S2 = h1c + MN;

  // 1+2. merged prep: x->bf16 (z=10) + all weight transposes (z<10) in one launch
  Prep tp;
  tp.s[0] = sd_w0;           tp.d[0] = wcat;            tp.ld[0] = D;
  tp.s[1] = rd_w0;           tp.d[1] = wcat + DD;       tp.ld[1] = D;
  tp.s[2] = rd_w0 + DD;      tp.d[2] = wcat + 2 * DD;   tp.ld[2] = D;
  tp.s[3] = sd_w1;           tp.d[3] = sdw1T;           tp.ld[3] = D;
  tp.s[4] = rd_w1;           tp.d[4] = rdw1T;           tp.ld[4] = D;
  tp.s[5] = af_w0;           tp.d[5] = afw0T;           tp.ld[5] = D;
  tp.s[6] = af_w1;           tp.d[6] = afw1T;           tp.ld[6] = D;
  tp.s[7] = ag_w1;           tp.d[7] = agw1T;           tp.ld[7] = D;
  tp.s[8] = ag_w0;           tp.d[8] = agw0T;           tp.ld[8] = 2 * D;
  tp.s[9] = ag_w0 + DD;      tp.d[9] = agw0T + D;       tp.ld[9] = 2 * D;
  tp.x = x; tp.xb = xb;
  k_prep<<<dim3(64, 64, 11), 256, 0, stream>>>(tp);

  dim3 g128(D / 256, M / 128);   // (8, 32) = 256 blocks, 100% fill, 1 round

  // 3+5 merged: tuv = [relu(xb@sd_w0+sd_b0) | xb@Wtop | xb@Wbot]  (N=6144)
  // 128x256 tile: grid (24,32)=768 blocks = exactly 3 rounds
  k_gemm<bf16_t, 128, 256, 8, 0><<<dim3(24, 32), 512, LDS128, stream>>>(
      xb, nullptr, D, 0, wcat, D, sd_b0, D, tuv, 3 * D, D, nullptr, 0);
  // 4. xs = relu(t0 @ sd_w1 + sd_b1)   (A = tuv t0-part, lda 6144)
  k_gemm<bf16_t, 128, 256, 8, 0><<<g128, 512, LDS128, stream>>>(
      tuv, nullptr, 3 * D, 0, sdw1T, D, sd_b1, D, xs, D, D, nullptr, 0);

  // 6-8. relational path: 2 chunks of 16384 padded pair-rows; fused group-reduce
  for (int c = 0; c < 2; ++c) {
    k_h1<<<dim3(MCP), 256, 0, stream>>>(tuv, 3 * D, D, 2 * D, rd_b0, h1c, c * MCP);
    k_gemm<bf16_t, 256, 256, 8, 1><<<dim3(D / 256, MCP / 256), 512, LDS256, stream>>>(
        h1c, nullptr, D, 0, rdw1T, D, rd_b1, D, predb, D, D, xs, c * 2048);
  }

  // 9. S1 = relu(pred @ af_w0 + af_b0)
  k_gemm<bf16_t, 128, 256, 8, 0><<<g128, 512, LDS128, stream>>>(
      predb, nullptr, D, 0, afw0T, D, af_b0, D, S1, D, D, nullptr, 0);
  // 10. S2 = relu(S1 @ af_w1 + af_b1)
  k_gemm<bf16_t, 128, 256, 8, 0><<<g128, 512, LDS128, stream>>>(
      S1, nullptr, D, 0, afw1T, D, af_b1, D, S2, D, D, nullptr, 0);
  // 11. S1 = relu([S2 ; xb] @ ag_w0 + ag_b0)  (virtual concat at k=D, K=4096)
  k_gemm<bf16_t, 128, 256, 8, 0><<<g128, 512, LDS128, stream>>>(
      S2, xb, D, D, agw0T, 2 * D, ag_b0, D, S1, D, 2 * D, nullptr, 0);
  // 12. out = relu(S1 @ ag_w1 + ag_b1) -> f32
  k_gemm<float, 128, 256, 8, 0><<<g128, 512, LDS128, stream>>>(
      S1, nullptr, D, 0, agw1T, D, ag_b1, D, out, D, D, nullptr, 0);
}